// Round 3
// baseline (313.123 us; speedup 1.0000x reference)
//
#include <hip/hip_runtime.h>

#define SEQ 2048
#define BATCH 4
#define DIM 1024
#define NHEAD 16
#define DHEAD 64

typedef __bf16 bf16;
typedef __bf16 bf16x8 __attribute__((ext_vector_type(8)));
typedef short bf16x4s __attribute__((ext_vector_type(4)));
typedef float f32x4 __attribute__((ext_vector_type(4)));
typedef unsigned int u32x4 __attribute__((ext_vector_type(4)));
typedef unsigned short u16;
typedef unsigned int u32;

__device__ __forceinline__ void gld16(const void* g, void* l) {
  __builtin_amdgcn_global_load_lds((__attribute__((address_space(1))) void*)(void*)g,
                                   (__attribute__((address_space(3))) void*)l, 16, 0, 0);
}

__device__ __forceinline__ u16 f2b(float f) {  // fp32 -> bf16 bits, RNE
  u32 u = __builtin_bit_cast(u32, f);
  u32 r = (u + 0x7FFFu + ((u >> 16) & 1u)) >> 16;
  return (u16)r;
}

// pack two f32 -> (bf16(f1)<<16)|bf16(f0), round-half-up (==RNE except exact ties)
__device__ __forceinline__ u32 pk2(float f0, float f1) {
  const u32 a = __builtin_bit_cast(u32, f1) + 0x8000u;
  const u32 b = __builtin_bit_cast(u32, f0) + 0x8000u;
  return __builtin_amdgcn_perm(a, b, 0x07060302u);
}

// K=16 bf16 MFMA: A/B = 4 bf16 (2 VGPR), layout A[m=lane&15][k=quad*4+j]
__device__ __forceinline__ f32x4 mfma16(bf16x4s a, bf16x4s b, f32x4 c) {
#if __has_builtin(__builtin_amdgcn_mfma_f32_16x16x16bf16_1k)
  return __builtin_amdgcn_mfma_f32_16x16x16bf16_1k(a, b, c, 0, 0, 0);
#else
  asm volatile("v_mfma_f32_16x16x16_bf16 %0, %1, %2, %0"
               : "+v"(c) : "v"(a), "v"(b));
  return c;
#endif
}

__device__ __forceinline__ void cvt16_store(const float4 v[4], u16* dst) {
  union { u16 h[16]; uint4 q[2]; } pk;
#pragma unroll
  for (int j = 0; j < 4; ++j) {
    pk.h[j * 4 + 0] = f2b(v[j].x);
    pk.h[j * 4 + 1] = f2b(v[j].y);
    pk.h[j * 4 + 2] = f2b(v[j].z);
    pk.h[j * 4 + 3] = f2b(v[j].w);
  }
  ((uint4*)dst)[0] = pk.q[0];
  ((uint4*)dst)[1] = pk.q[1];
}

// ---------------- K0: one-shot f32 -> bf16 conversion ----------------
__global__ __launch_bounds__(256) void k_cvt(
    const float* __restrict__ inp, const float* __restrict__ wqkv,
    const float* __restrict__ wproj, u16* __restrict__ xb,
    u16* __restrict__ wqkvb, u16* __restrict__ wprojb) {
  const int idx = blockIdx.x * 256 + threadIdx.x;
  const float4* src;
  u16* dst;
  int off;
  if (idx < 2097152)      { src = (const float4*)inp;   dst = xb;     off = idx; }
  else if (idx < 2883584) { src = (const float4*)wqkv;  dst = wqkvb;  off = idx - 2097152; }
  else                    { src = (const float4*)wproj; dst = wprojb; off = idx - 2883584; }
  const float4 v = src[off];
  union { u16 h[4]; uint2 q; } pk;
  pk.h[0] = f2b(v.x); pk.h[1] = f2b(v.y); pk.h[2] = f2b(v.z); pk.h[3] = f2b(v.w);
  *(uint2*)(dst + (size_t)off * 4) = pk.q;
}

// ---------------- K1a: QKV projection, all-bf16, async staging ----------------
__global__ __launch_bounds__(256, 2) void k_qkv_a(
    const u16* __restrict__ xb, const u16* __restrict__ wb,
    const float* __restrict__ bqkv, u16* __restrict__ q,
    u16* __restrict__ kk, u16* __restrict__ v) {
  __shared__ __align__(16) u16 Asm[128 * 32];
  __shared__ __align__(16) u16 Bsm[128 * 32];
  const int bn = blockIdx.x;   // 0..23
  const int bm = blockIdx.y;   // 0..63
  const int tid = threadIdx.x;
  const int wave = tid >> 6, lane = tid & 63;
  const int col = lane & 15, quad = lane >> 4;
  const int b = bm >> 4;
  const int s0 = (bm & 15) * 128;
  const int c0 = wave * 2;
  const int srow0 = c0 * 16 + (lane >> 2);
  const int kc = (lane & 3) * 8;
  const u16* gA0 = xb + (size_t)((s0 + srow0) * 4 + b) * 1024 + kc;
  const u16* gA1 = xb + (size_t)((s0 + srow0 + 16) * 4 + b) * 1024 + kc;
  const u16* gB0 = wb + (size_t)(bn * 128 + srow0) * 1024 + kc;
  const u16* gB1 = wb + (size_t)(bn * 128 + srow0 + 16) * 1024 + kc;
  u16* lA0 = Asm + c0 * 512;
  u16* lA1 = Asm + c0 * 512 + 512;
  u16* lB0 = Bsm + c0 * 512;
  u16* lB1 = Bsm + c0 * 512 + 512;
  const int wm = (wave >> 1) * 64, wn = (wave & 1) * 64;

  f32x4 acc[4][4];
#pragma unroll
  for (int i = 0; i < 4; ++i)
#pragma unroll
    for (int j = 0; j < 4; ++j) acc[i][j] = f32x4{0.f, 0.f, 0.f, 0.f};

  for (int k0 = 0; k0 < 1024; k0 += 32) {
    __syncthreads();
    gld16(gA0 + k0, lA0);
    gld16(gA1 + k0, lA1);
    gld16(gB0 + k0, lB0);
    gld16(gB1 + k0, lB1);
    __builtin_amdgcn_s_waitcnt(0);
    __syncthreads();
    bf16x8 af[4], bfr[4];
#pragma unroll
    for (int i = 0; i < 4; ++i)
      af[i] = *(const bf16x8*)(Asm + (wm + i * 16 + col) * 32 + quad * 8);
#pragma unroll
    for (int j = 0; j < 4; ++j)
      bfr[j] = *(const bf16x8*)(Bsm + (wn + j * 16 + col) * 32 + quad * 8);
#pragma unroll
    for (int i = 0; i < 4; ++i)
#pragma unroll
      for (int j = 0; j < 4; ++j)
        acc[i][j] = __builtin_amdgcn_mfma_f32_16x16x32_bf16(af[i], bfr[j], acc[i][j], 0, 0, 0);
  }

  const float QS = 0.125f * 1.44269504088896f;  // SCALE * log2(e)
#pragma unroll
  for (int j = 0; j < 4; ++j) {
    const int n = bn * 128 + wn + j * 16 + col;
    const float bias = bqkv[n];
    const int region = n >> 10;  // 0=q 1=k 2=v
    const int hh = (n >> 6) & 15;
    const int dh = n & 63;
    if (region == 2) {  // V transposed: [B,H,DH,S]
      const size_t baseT = ((size_t)(b * 16 + hh) * 64 + dh) * 2048;
#pragma unroll
      for (int i = 0; i < 4; ++i) {
        const int srow = s0 + wm + i * 16 + quad * 4;
#pragma unroll
        for (int r = 0; r < 4; ++r)
          v[baseT + srow + r] = f2b(acc[i][j][r] + bias);
      }
    } else {
      u16* outp = (region == 0) ? q : kk;
      const float mult = (region == 0) ? QS : 1.0f;
      const size_t base = ((size_t)(b * 16 + hh) * 2048) * 64 + dh;
#pragma unroll
      for (int i = 0; i < 4; ++i) {
        const int srow = s0 + wm + i * 16 + quad * 4;
#pragma unroll
        for (int r = 0; r < 4; ++r)
          outp[base + (size_t)(srow + r) * 64] = f2b((acc[i][j][r] + bias) * mult);
      }
    }
  }
}

// ---------------- K1b: QKV projection, f32-inline-convert (fallback) ----------------
__global__ __launch_bounds__(256, 2) void k_qkv_f32(
    const float* __restrict__ inp, const float* __restrict__ Wqkv,
    const float* __restrict__ bqkv, u16* __restrict__ q,
    u16* __restrict__ kk, u16* __restrict__ v, int b_fixed) {
  __shared__ __align__(16) u16 Asm[128 * 32];
  __shared__ __align__(16) u16 Bsm[128 * 32];
  const int bn = blockIdx.x;
  const int bm = blockIdx.y;
  const int tid = threadIdx.x;
  const int wave = tid >> 6, lane = tid & 63;
  const int col = lane & 15, quad = lane >> 4;
  int b, s0, hb;
  if (b_fixed < 0) { b = bm >> 4; s0 = (bm & 15) * 128; hb = b * 16; }
  else             { b = b_fixed; s0 = bm * 128;        hb = 0; }

  const int arow = tid >> 1;
  const int kseg = (tid & 1) * 16;
  const float* gA = inp + (size_t)((s0 + arow) * 4 + b) * 1024 + kseg;
  const float* gB = Wqkv + (size_t)(bn * 128 + arow) * 1024 + kseg;
  u16* lA = Asm + arow * 32 + kseg;
  u16* lB = Bsm + arow * 32 + kseg;
  const int wm = (wave >> 1) * 64, wn = (wave & 1) * 64;

  f32x4 acc[4][4];
#pragma unroll
  for (int i = 0; i < 4; ++i)
#pragma unroll
    for (int j = 0; j < 4; ++j) acc[i][j] = f32x4{0.f, 0.f, 0.f, 0.f};

  for (int k0 = 0; k0 < 1024; k0 += 32) {
    float4 av[4], bv[4];
#pragma unroll
    for (int u = 0; u < 4; ++u) av[u] = *(const float4*)(gA + k0 + u * 4);
#pragma unroll
    for (int u = 0; u < 4; ++u) bv[u] = *(const float4*)(gB + k0 + u * 4);
    __syncthreads();
    cvt16_store(av, lA);
    cvt16_store(bv, lB);
    __syncthreads();
    bf16x8 af[4], bfr[4];
#pragma unroll
    for (int i = 0; i < 4; ++i)
      af[i] = *(const bf16x8*)(Asm + (wm + i * 16 + col) * 32 + quad * 8);
#pragma unroll
    for (int j = 0; j < 4; ++j)
      bfr[j] = *(const bf16x8*)(Bsm + (wn + j * 16 + col) * 32 + quad * 8);
#pragma unroll
    for (int i = 0; i < 4; ++i)
#pragma unroll
      for (int j = 0; j < 4; ++j)
        acc[i][j] = __builtin_amdgcn_mfma_f32_16x16x32_bf16(af[i], bfr[j], acc[i][j], 0, 0, 0);
  }

  const float QS = 0.125f * 1.44269504088896f;
#pragma unroll
  for (int j = 0; j < 4; ++j) {
    const int n = bn * 128 + wn + j * 16 + col;
    const float bias = bqkv[n];
    const int region = n >> 10;
    const int hh = (n >> 6) & 15;
    const int dh = n & 63;
    if (region == 2) {
      const size_t baseT = ((size_t)(hb + hh) * 64 + dh) * 2048;
#pragma unroll
      for (int i = 0; i < 4; ++i) {
        const int srow = s0 + wm + i * 16 + quad * 4;
#pragma unroll
        for (int r = 0; r < 4; ++r)
          v[baseT + srow + r] = f2b(acc[i][j][r] + bias);
      }
    } else {
      u16* outp = (region == 0) ? q : kk;
      const float mult = (region == 0) ? QS : 1.0f;
      const size_t base = ((size_t)(hb + hh) * 2048) * 64 + dh;
#pragma unroll
      for (int i = 0; i < 4; ++i) {
        const int srow = s0 + wm + i * 16 + quad * 4;
#pragma unroll
        for (int r = 0; r < 4; ++r)
          outp[base + (size_t)(srow + r) * 64] = f2b((acc[i][j][r] + bias) * mult);
      }
    }
  }
}

// ---------------- K2: flash attention, relay-free PV via 16x16x16 MFMA ----------------
// R11: R10 post-mortem: dur unchanged vs R8 (140us) -> the stage-drain was
// never critical (TLP covered it). Counters: VALUBusy 52%, MfmaUtil 21% ->
// bound by softmax VALU + the P-relay LDS round-trip (4x lgkmcnt(0) drains
// per iter, ~120cy each, on the dependency chain). Fix: PV now uses
// v_mfma_f32_16x16x16_bf16 whose A-operand layout (A[m=lane&15][k=quad*4+j])
// EXACTLY matches the QK D-layout (P[q=col][key=quad*4+r]) -> P stays in
// registers, relay deleted (32 ds-ops + 4 drains gone, LDS 40->32KB).
// V B-fragment becomes ds_read_b64 of keys quad*4+{0..3} from the same
// chunk-XOR'd Vsm (predicted ~4-way bank aliasing, cheap per m136).
// PV MFMA count doubles (16x16x16 instrs) - matrix pipe at 21% has headroom.
// Keeps: R9 XCD swizzle (FETCH 144->25MB), R10 double-buffer + 1 barrier,
// setprio around MFMA clusters.
__global__ __launch_bounds__(256, 4) void k_attn(
    const u16* __restrict__ q, const u16* __restrict__ k,
    const u16* __restrict__ v, const int* __restrict__ mask,
    u16* __restrict__ attn, int b_fixed) {
  __shared__ __align__(16) u16 Ksm[2][64 * 64];  // 16KB double-buffered
  __shared__ __align__(16) u16 Vsm[2][64 * 64];  // 16KB double-buffered
  const int bid = blockIdx.x;
  const int tid = threadIdx.x, wave = tid >> 6, lane = tid & 63;
  const int col = lane & 15, quad = lane >> 4;
  int qblk, h, b, hb;
  if (b_fixed < 0) {
    // work id w: group w>>4 = (b,h); all 16 q-blocks of a group on one XCD
    const int w = ((bid & 7) << 7) | (bid >> 3);
    qblk = w & 15; h = (w >> 4) & 15; b = w >> 8; hb = b * 16 + h;
  } else {
    qblk = bid & 15; h = bid >> 4; b = b_fixed; hb = h;
  }
  const size_t bh = (size_t)hb * 2048 * 64;
  const int* mrow = mask + b * 2048;

  bf16x8 qf[2][2];
#pragma unroll
  for (int qt = 0; qt < 2; ++qt)
#pragma unroll
    for (int c = 0; c < 2; ++c)
      qf[qt][c] = *(const bf16x8*)(q + bh +
                   (size_t)(qblk * 128 + wave * 32 + qt * 16 + col) * 64 + c * 32 + quad * 8);

  const int r8 = lane >> 3, chn = lane & 7;
  const int g = chn ^ r8;
  const int swz = col & 7;

  // cooperative stage of one 64-key K/V tile into buffer `buf`
  auto STAGE = [&](int buf, int kt) {
#pragma unroll
    for (int s = 0; s < 2; ++s) {
      const int row = (wave * 2 + s) * 8 + r8;
      gld16(k + bh + (size_t)(kt * 64 + row) * 64 + g * 8,
            (char*)Ksm[buf] + (wave * 2 + s) * 1024);
      gld16(v + bh + (size_t)row * 2048 + kt * 64 + g * 8,
            (char*)Vsm[buf] + (wave * 2 + s) * 1024);
    }
  };

  f32x4 o[2][4];
#pragma unroll
  for (int qt = 0; qt < 2; ++qt)
#pragma unroll
    for (int n = 0; n < 4; ++n) o[qt][n] = f32x4{0.f, 0.f, 0.f, 0.f};
  float mrun[2] = {-1e30f, -1e30f}, lrun[2] = {0.f, 0.f};

  // prologue: stage kt=0 into buffer 0
  STAGE(0, 0);
  asm volatile("s_waitcnt vmcnt(0)" ::: "memory");
  __syncthreads();

  int cur = 0;
  for (int kt = 0; kt < 32; ++kt) {
    // mask words first, converted to bias immediately (frees the int regs)
    f32x4 mb[4];
#pragma unroll
    for (int mt = 0; mt < 4; ++mt) {
      const int4 mi = *(const int4*)(mrow + kt * 64 + mt * 16 + quad * 4);
      mb[mt][0] = (mi.x != 0) ? -1e30f : 0.f;
      mb[mt][1] = (mi.y != 0) ? -1e30f : 0.f;
      mb[mt][2] = (mi.z != 0) ? -1e30f : 0.f;
      mb[mt][3] = (mi.w != 0) ? -1e30f : 0.f;
    }
    __builtin_amdgcn_sched_barrier(0);  // pin: mask loads before stage loads
    if (kt < 31) STAGE(cur ^ 1, kt + 1);

    // ---- QK: mt-outer, mask bias as C-init ----
    f32x4 sc[2][4];  // [qt][mt]
    __builtin_amdgcn_s_setprio(1);
#pragma unroll
    for (int mt = 0; mt < 4; ++mt) {
      const bf16x8 ka0 = *(const bf16x8*)((const char*)Ksm[cur] +
          (mt * 16 + col) * 128 + (quad ^ swz) * 16);
      const bf16x8 ka1 = *(const bf16x8*)((const char*)Ksm[cur] +
          (mt * 16 + col) * 128 + ((4 + quad) ^ swz) * 16);
#pragma unroll
      for (int qt = 0; qt < 2; ++qt) {
        f32x4 z = mb[mt];
        z = __builtin_amdgcn_mfma_f32_16x16x32_bf16(ka0, qf[qt][0], z, 0, 0, 0);
        sc[qt][mt] = __builtin_amdgcn_mfma_f32_16x16x32_bf16(ka1, qf[qt][1], z, 0, 0, 0);
      }
    }
    __builtin_amdgcn_s_setprio(0);

    // ---- online softmax, P packed IN-REGISTER as 16x16x16 A-fragments ----
    float alpha[2];
    bf16x4s pa[2][4];  // [qt][mt]: P[q=col][key=quad*4+j] -- matches sc layout
#pragma unroll
    for (int qt = 0; qt < 2; ++qt) {
      float tm = fmaxf(fmaxf(sc[qt][0][0], sc[qt][0][1]),
                       fmaxf(sc[qt][0][2], sc[qt][0][3]));
#pragma unroll
      for (int mt = 1; mt < 4; ++mt)
#pragma unroll
        for (int r = 0; r < 4; ++r) tm = fmaxf(tm, sc[qt][mt][r]);
      tm = fmaxf(tm, __shfl_xor(tm, 16, 64));
      tm = fmaxf(tm, __shfl_xor(tm, 32, 64));
      const float mnew = fmaxf(mrun[qt], tm);
      alpha[qt] = __builtin_amdgcn_exp2f(mrun[qt] - mnew);
      mrun[qt] = mnew;
      float sum = 0.f;
#pragma unroll
      for (int mt = 0; mt < 4; ++mt)
#pragma unroll
        for (int r = 0; r < 4; ++r) {
          sc[qt][mt][r] = __builtin_amdgcn_exp2f(sc[qt][mt][r] - mnew);
          sum += sc[qt][mt][r];
        }
      sum += __shfl_xor(sum, 16, 64);
      sum += __shfl_xor(sum, 32, 64);
      lrun[qt] = lrun[qt] * alpha[qt] + sum;
#pragma unroll
      for (int mt = 0; mt < 4; ++mt) {
        uint2 w;
        w.x = pk2(sc[qt][mt][0], sc[qt][mt][1]);
        w.y = pk2(sc[qt][mt][2], sc[qt][mt][3]);
        pa[qt][mt] = __builtin_bit_cast(bf16x4s, w);
      }
    }

    float ar[2][4];
#pragma unroll
    for (int qt = 0; qt < 2; ++qt)
#pragma unroll
      for (int r = 0; r < 4; ++r) ar[qt][r] = __shfl(alpha[qt], quad * 4 + r, 64);

    // ---- PV: K=16 MFMAs, V fragments as ds_read_b64 (keys quad*4..+3) ----
    __builtin_amdgcn_s_setprio(1);
#pragma unroll
    for (int nt = 0; nt < 4; ++nt) {
      bf16x4s vb[4];
#pragma unroll
      for (int mt = 0; mt < 4; ++mt) {
        // Vsm row = dh = nt*16+col; stored 16B-chunk p holds keys (p^swz)*8
        const uint2 raw = *(const uint2*)((const char*)Vsm[cur] +
            (nt * 16 + col) * 128 + (((mt * 2 + (quad >> 1)) ^ swz) << 4) +
            ((quad & 1) << 3));
        vb[mt] = __builtin_bit_cast(bf16x4s, raw);
      }
#pragma unroll
      for (int qt = 0; qt < 2; ++qt) {
        f32x4 t = o[qt][nt];
#pragma unroll
        for (int r = 0; r < 4; ++r) t[r] *= ar[qt][r];
#pragma unroll
        for (int mt = 0; mt < 4; ++mt) t = mfma16(pa[qt][mt], vb[mt], t);
        o[qt][nt] = t;
      }
    }
    __builtin_amdgcn_s_setprio(0);

    // next-tile loads were issued ~one full compute phase ago
    asm volatile("s_waitcnt vmcnt(0)" ::: "memory");
    __syncthreads();
    cur ^= 1;
  }

  const int arow0 = (b_fixed < 0) ? b * 2048 : 0;
#pragma unroll
  for (int qt = 0; qt < 2; ++qt) {
    float inv[4];
#pragma unroll
    for (int r = 0; r < 4; ++r) {
      const float lr = __shfl(lrun[qt], quad * 4 + r, 64);
      inv[r] = 1.0f / lr;
    }
#pragma unroll
    for (int n = 0; n < 4; ++n)
#pragma unroll
      for (int r = 0; r < 4; ++r) {
        const int srow = qblk * 128 + wave * 32 + qt * 16 + quad * 4 + r;
        const size_t idx = ((size_t)(arow0 + srow)) * 1024 + h * 64 + n * 16 + col;
        attn[idx] = f2b(o[qt][n][r] * inv[r]);
      }
  }
}

// ---------------- K3a: output projection, all-bf16 staging ----------------
__global__ __launch_bounds__(256, 2) void k_proj_a(
    const u16* __restrict__ attn, const u16* __restrict__ wb,
    const float* __restrict__ bproj, float* __restrict__ out) {
  __shared__ __align__(16) u16 Asm[128 * 32];
  __shared__ __align__(16) u16 Bsm[128 * 32];
  const int bn = blockIdx.x;  // 0..7
  const int bm = blockIdx.y;  // 0..63
  const int tid = threadIdx.x;
  const int wave = tid >> 6, lane = tid & 63;
  const int col = lane & 15, quad = lane >> 4;
  const int b = bm >> 4;
  const int s0 = (bm & 15) * 128;
  const int c0 = wave * 2;
  const int srow0 = c0 * 16 + (lane >> 2);
  const int kc = (lane & 3) * 8;
  const u16* gA0 = attn + (size_t)(bm * 128 + srow0) * 1024 + kc;
  const u16* gA1 = attn + (size_t)(bm * 128 + srow0 + 16) * 1024 + kc;
  const u16* gB0 = wb + (size_t)(bn * 128 + srow0) * 1024 + kc;
  const u16* gB1 = wb + (size_t)(bn * 128 + srow0 + 16) * 1024 + kc;
  u16* lA0 = Asm + c0 * 512;
  u16* lA1 = Asm + c0 * 512 + 512;
  u16* lB0 = Bsm + c0 * 512;
  u16* lB1 = Bsm + c0 * 512 + 512;
  const int wm = (wave >> 1) * 64, wn = (wave & 1) * 64;

  f32x4 acc[4][4];
#pragma unroll
  for (int i = 0; i < 4; ++i)
#pragma unroll
    for (int j = 0; j < 4; ++j) acc[i][j] = f32x4{0.f, 0.f, 0.f, 0.f};

  for (int k0 = 0; k0 < 1024; k0 += 32) {
    __syncthreads();
    gld16(gA0 + k0, lA0);
    gld16(gA1 + k0, lA1);
    gld16(gB0 + k0, lB0);
    gld16(gB1 + k0, lB1);
    __builtin_amdgcn_s_waitcnt(0);
    __syncthreads();
    bf16x8 af[4], bfr[4];
#pragma unroll
    for (int i = 0; i < 4; ++i)
      af[i] = *(const bf16x8*)(Asm + (wm + i * 16 + col) * 32 + quad * 8);
#pragma unroll
    for (int j = 0; j < 4; ++j)
      bfr[j] = *(const bf16x8*)(Bsm + (wn + j * 16 + col) * 32 + quad * 8);
#pragma unroll
    for (int i = 0; i < 4; ++i)
#pragma unroll
      for (int j = 0; j < 4; ++j)
        acc[i][j] = __builtin_amdgcn_mfma_f32_16x16x32_bf16(af[i], bfr[j], acc[i][j], 0, 0, 0);
  }

#pragma unroll
  for (int j = 0; j < 4; ++j) {
    const int n = bn * 128 + wn + j * 16 + col;
    const float bias = bproj[n];
#pragma unroll
    for (int i = 0; i < 4; ++i) {
      const int srow = s0 + wm + i * 16 + quad * 4;
#pragma unroll
      for (int r = 0; r < 4; ++r)
        out[(size_t)((srow + r) * 4 + b) * 1024 + n] = acc[i][j][r] + bias;
    }
  }
}

// ---------------- K3b: output projection, inline-convert B (fallback) ----------------
__global__ __launch_bounds__(256, 2) void k_proj_f32(
    const u16* __restrict__ attn, const float* __restrict__ Wproj,
    const float* __restrict__ bproj, float* __restrict__ out, int b_fixed) {
  __shared__ __align__(16) u16 Asm[128 * 32];
  __shared__ __align__(16) u16 Bsm[128 * 32];
  const int bn = blockIdx.x;
  const int bm = blockIdx.y;
  const int tid = threadIdx.x;
  const int wave = tid >> 6, lane = tid & 63;
  const int col = lane & 15, quad = lane >> 4;
  int b, s0;
  if (b_fixed < 0) { b = bm >> 4; s0 = (bm & 15) * 128; }
  else             { b = b_fixed; s0 = bm * 128; }

  const int c0 = wave * 2;
  const int srow0 = c0 * 16 + (lane >> 2);
  const int kc = (lane & 3) * 8;
  const u16* gA0 = attn + (size_t)(bm * 128 + srow0) * 1024 + kc;
  const u16* gA1 = attn + (size_t)(bm * 128 + srow0 + 16) * 1024 + kc;
  u16* lA0 = Asm + c0 * 512;
  u16* lA1 = Asm + c0 * 512 + 512;
  const int brow = tid >> 1;
  const int kseg = (tid & 1) * 16;
  const float* gB = Wproj + (size_t)(bn * 128 + brow) * 1024 + kseg;
  u16* lB = Bsm + brow * 32 + kseg;
  const int wm = (wave >> 1) * 64, wn = (wave & 1) * 64;

  f32x4 acc[4][4];
#pragma unroll
  for (int i = 0; i < 4; ++i)
#pragma unroll
    for (int j = 0; j < 4; ++j) acc[i][j] = f32x4{0.f, 0.f, 0.f, 0.f};

  for (int k0 = 0; k0 < 1024; k0 += 32) {
    float4 bv[4];
#pragma unroll
    for (int u = 0; u < 4; ++u) bv[u] = *(const float4*)(gB + k0 + u * 4);
    __syncthreads();
    gld16(gA0 + k0, lA0);
    gld16(gA1 + k0, lA1);
    cvt16_store(bv, lB);
    __builtin_amdgcn_s_waitcnt(0);
    __syncthreads();
    bf16x8 af[4], bfr[4];
#pragma unroll
    for (int i = 0; i < 4; ++i)
      af[i] = *(const bf16x8*)(Asm + (wm + i * 16 + col) * 32 + quad * 8);
#pragma unroll
    for (int j = 0; j < 4; ++j)
      bfr[j] = *(const bf16x8*)(Bsm + (wn + j * 16 + col) * 32 + quad * 8);
#pragma unroll
    for (int i = 0; i < 4; ++i)
#pragma unroll
      for (int j = 0; j < 4; ++j)
        acc[i][j] = __builtin_amdgcn_mfma_f32_16x16x32_bf16(af[i], bfr[j], acc[i][j], 0, 0, 0);
  }

#pragma unroll
  for (int j = 0; j < 4; ++j) {
    const int n = bn * 128 + wn + j * 16 + col;
    const float bias = bproj[n];
#pragma unroll
    for (int i = 0; i < 4; ++i) {
      const int srow = s0 + wm + i * 16 + quad * 4;
#pragma unroll
      for (int r = 0; r < 4; ++r)
        out[(size_t)((srow + r) * 4 + b) * 1024 + n] = acc[i][j][r] + bias;
    }
  }
}

extern "C" void kernel_launch(void* const* d_in, const int* in_sizes, int n_in,
                              void* d_out, int out_size, void* d_ws, size_t ws_size,
                              hipStream_t stream) {
  const float* inp = (const float*)d_in[0];
  const int* mask = (const int*)d_in[1];
  const float* Wqkv = (const float*)d_in[2];
  const float* bqkv = (const float*)d_in[3];
  const float* Wproj = (const float*)d_in[4];
  const float* bproj = (const float*)d_in[5];
  float* out = (float*)d_out;

  const size_t FULLSZ = (size_t)BATCH * NHEAD * SEQ * DHEAD;  // 8388608 elems
  const size_t WQKV_E = (size_t)3 * DIM * DIM;                // 3145728
  const size_t WPROJ_E = (size_t)DIM * DIM;                   // 1048576
  const size_t pathA_bytes = (4 * FULLSZ + WQKV_E + WPROJ_E) * sizeof(u16);  // 75.5 MB

  if (ws_size >= pathA_bytes) {
    // Path A: convert-once + all-async-bf16 GEMMs.
    u16* q = (u16*)d_ws;
    u16* kk = q + FULLSZ;
    u16* v = kk + FULLSZ;
    u16* xb = v + FULLSZ;      // converted inp; later overwritten as attn buffer
    u16* attn = xb;            // alias — k_attn writes after k_qkv_a finished reading
    u16* wqkvb = xb + FULLSZ;
    u16* wprojb = wqkvb + WQKV_E;
    k_cvt<<<dim3(12288), 256, 0, stream>>>(inp, Wqkv, Wproj, xb, wqkvb, wprojb);
    k_qkv_a<<<dim3(24, 64), 256, 0, stream>>>(xb, wqkvb, bqkv, q, kk, v);
    k_attn<<<dim3(1024), 256, 0, stream>>>(q, kk, v, mask, attn, -1);
    k_proj_a<<<dim3(8, 64), 256, 0, stream>>>(attn, wprojb, bproj, out);
  } else if (ws_size >= 4 * FULLSZ * sizeof(u16)) {
    // Path B: proven R5 pipeline (inline f32 convert).
    u16* q = (u16*)d_ws;
    u16* kk = q + FULLSZ;
    u16* v = kk + FULLSZ;
    u16* attn = v + FULLSZ;
    k_qkv_f32<<<dim3(24, 64), 256, 0, stream>>>(inp, Wqkv, bqkv, q, kk, v, -1);
    k_attn<<<dim3(1024), 256, 0, stream>>>(q, kk, v, mask, attn, -1);
    k_proj_f32<<<dim3(8, 64), 256, 0, stream>>>(attn, Wproj, bproj, out, -1);
  } else {
    // Path C: per-batch pipeline, 16 MiB workspace.
    const size_t BSZ = (size_t)NHEAD * SEQ * DHEAD;
    u16* q = (u16*)d_ws;
    u16* kk = q + BSZ;
    u16* v = kk + BSZ;
    u16* attn = v + BSZ;
    for (int b = 0; b < BATCH; ++b) {
      k_qkv_f32<<<dim3(24, 16), 256, 0, stream>>>(inp, Wqkv, bqkv, q, kk, v, b);
      k_attn<<<dim3(256), 256, 0, stream>>>(q, kk, v, mask, attn, b);
      k_proj_f32<<<dim3(8, 16), 256, 0, stream>>>(attn, Wproj, bproj, out, b);
    }
  }
}

// Round 4
// 307.149 us; speedup vs baseline: 1.0194x; 1.0194x over previous
//
#include <hip/hip_runtime.h>

#define SEQ 2048
#define BATCH 4
#define DIM 1024
#define NHEAD 16
#define DHEAD 64

typedef __bf16 bf16;
typedef __bf16 bf16x8 __attribute__((ext_vector_type(8)));
typedef short bf16x4s __attribute__((ext_vector_type(4)));
typedef float f32x4 __attribute__((ext_vector_type(4)));
typedef unsigned int u32x4 __attribute__((ext_vector_type(4)));
typedef unsigned short u16;
typedef unsigned int u32;

__device__ __forceinline__ void gld16(const void* g, void* l) {
  __builtin_amdgcn_global_load_lds((__attribute__((address_space(1))) void*)(void*)g,
                                   (__attribute__((address_space(3))) void*)l, 16, 0, 0);
}

__device__ __forceinline__ u16 f2b(float f) {  // fp32 -> bf16 bits, RNE
  u32 u = __builtin_bit_cast(u32, f);
  u32 r = (u + 0x7FFFu + ((u >> 16) & 1u)) >> 16;
  return (u16)r;
}

// pack two f32 -> (bf16(f1)<<16)|bf16(f0), round-half-up (==RNE except exact ties)
__device__ __forceinline__ u32 pk2(float f0, float f1) {
  const u32 a = __builtin_bit_cast(u32, f1) + 0x8000u;
  const u32 b = __builtin_bit_cast(u32, f0) + 0x8000u;
  return __builtin_amdgcn_perm(a, b, 0x07060302u);
}

// K=16 bf16 MFMA: A/B = 4 bf16 (2 VGPR), layout A[m=lane&15][k=quad*4+j]
__device__ __forceinline__ f32x4 mfma16(bf16x4s a, bf16x4s b, f32x4 c) {
#if __has_builtin(__builtin_amdgcn_mfma_f32_16x16x16bf16_1k)
  return __builtin_amdgcn_mfma_f32_16x16x16bf16_1k(a, b, c, 0, 0, 0);
#else
  asm volatile("v_mfma_f32_16x16x16_bf16 %0, %1, %2, %0"
               : "+v"(c) : "v"(a), "v"(b));
  return c;
#endif
}

__device__ __forceinline__ void cvt16_store(const float4 v[4], u16* dst) {
  union { u16 h[16]; uint4 q[2]; } pk;
#pragma unroll
  for (int j = 0; j < 4; ++j) {
    pk.h[j * 4 + 0] = f2b(v[j].x);
    pk.h[j * 4 + 1] = f2b(v[j].y);
    pk.h[j * 4 + 2] = f2b(v[j].z);
    pk.h[j * 4 + 3] = f2b(v[j].w);
  }
  ((uint4*)dst)[0] = pk.q[0];
  ((uint4*)dst)[1] = pk.q[1];
}

// ---------------- K0: one-shot f32 -> bf16 conversion ----------------
__global__ __launch_bounds__(256) void k_cvt(
    const float* __restrict__ inp, const float* __restrict__ wqkv,
    const float* __restrict__ wproj, u16* __restrict__ xb,
    u16* __restrict__ wqkvb, u16* __restrict__ wprojb) {
  const int idx = blockIdx.x * 256 + threadIdx.x;
  const float4* src;
  u16* dst;
  int off;
  if (idx < 2097152)      { src = (const float4*)inp;   dst = xb;     off = idx; }
  else if (idx < 2883584) { src = (const float4*)wqkv;  dst = wqkvb;  off = idx - 2097152; }
  else                    { src = (const float4*)wproj; dst = wprojb; off = idx - 2883584; }
  const float4 v = src[off];
  union { u16 h[4]; uint2 q; } pk;
  pk.h[0] = f2b(v.x); pk.h[1] = f2b(v.y); pk.h[2] = f2b(v.z); pk.h[3] = f2b(v.w);
  *(uint2*)(dst + (size_t)off * 4) = pk.q;
}

// ---------------- K1a: QKV projection, all-bf16, async staging ----------------
__global__ __launch_bounds__(256, 2) void k_qkv_a(
    const u16* __restrict__ xb, const u16* __restrict__ wb,
    const float* __restrict__ bqkv, u16* __restrict__ q,
    u16* __restrict__ kk, u16* __restrict__ v) {
  __shared__ __align__(16) u16 Asm[128 * 32];
  __shared__ __align__(16) u16 Bsm[128 * 32];
  const int bn = blockIdx.x;   // 0..23
  const int bm = blockIdx.y;   // 0..63
  const int tid = threadIdx.x;
  const int wave = tid >> 6, lane = tid & 63;
  const int col = lane & 15, quad = lane >> 4;
  const int b = bm >> 4;
  const int s0 = (bm & 15) * 128;
  const int c0 = wave * 2;
  const int srow0 = c0 * 16 + (lane >> 2);
  const int kc = (lane & 3) * 8;
  const u16* gA0 = xb + (size_t)((s0 + srow0) * 4 + b) * 1024 + kc;
  const u16* gA1 = xb + (size_t)((s0 + srow0 + 16) * 4 + b) * 1024 + kc;
  const u16* gB0 = wb + (size_t)(bn * 128 + srow0) * 1024 + kc;
  const u16* gB1 = wb + (size_t)(bn * 128 + srow0 + 16) * 1024 + kc;
  u16* lA0 = Asm + c0 * 512;
  u16* lA1 = Asm + c0 * 512 + 512;
  u16* lB0 = Bsm + c0 * 512;
  u16* lB1 = Bsm + c0 * 512 + 512;
  const int wm = (wave >> 1) * 64, wn = (wave & 1) * 64;

  f32x4 acc[4][4];
#pragma unroll
  for (int i = 0; i < 4; ++i)
#pragma unroll
    for (int j = 0; j < 4; ++j) acc[i][j] = f32x4{0.f, 0.f, 0.f, 0.f};

  for (int k0 = 0; k0 < 1024; k0 += 32) {
    __syncthreads();
    gld16(gA0 + k0, lA0);
    gld16(gA1 + k0, lA1);
    gld16(gB0 + k0, lB0);
    gld16(gB1 + k0, lB1);
    __builtin_amdgcn_s_waitcnt(0);
    __syncthreads();
    bf16x8 af[4], bfr[4];
#pragma unroll
    for (int i = 0; i < 4; ++i)
      af[i] = *(const bf16x8*)(Asm + (wm + i * 16 + col) * 32 + quad * 8);
#pragma unroll
    for (int j = 0; j < 4; ++j)
      bfr[j] = *(const bf16x8*)(Bsm + (wn + j * 16 + col) * 32 + quad * 8);
#pragma unroll
    for (int i = 0; i < 4; ++i)
#pragma unroll
      for (int j = 0; j < 4; ++j)
        acc[i][j] = __builtin_amdgcn_mfma_f32_16x16x32_bf16(af[i], bfr[j], acc[i][j], 0, 0, 0);
  }

  const float QS = 0.125f * 1.44269504088896f;  // SCALE * log2(e)
#pragma unroll
  for (int j = 0; j < 4; ++j) {
    const int n = bn * 128 + wn + j * 16 + col;
    const float bias = bqkv[n];
    const int region = n >> 10;  // 0=q 1=k 2=v
    const int hh = (n >> 6) & 15;
    const int dh = n & 63;
    if (region == 2) {  // V transposed: [B,H,DH,S]
      const size_t baseT = ((size_t)(b * 16 + hh) * 64 + dh) * 2048;
#pragma unroll
      for (int i = 0; i < 4; ++i) {
        const int srow = s0 + wm + i * 16 + quad * 4;
#pragma unroll
        for (int r = 0; r < 4; ++r)
          v[baseT + srow + r] = f2b(acc[i][j][r] + bias);
      }
    } else {
      u16* outp = (region == 0) ? q : kk;
      const float mult = (region == 0) ? QS : 1.0f;
      const size_t base = ((size_t)(b * 16 + hh) * 2048) * 64 + dh;
#pragma unroll
      for (int i = 0; i < 4; ++i) {
        const int srow = s0 + wm + i * 16 + quad * 4;
#pragma unroll
        for (int r = 0; r < 4; ++r)
          outp[base + (size_t)(srow + r) * 64] = f2b((acc[i][j][r] + bias) * mult);
      }
    }
  }
}

// ---------------- K1b: QKV projection, f32-inline-convert (fallback) ----------------
__global__ __launch_bounds__(256, 2) void k_qkv_f32(
    const float* __restrict__ inp, const float* __restrict__ Wqkv,
    const float* __restrict__ bqkv, u16* __restrict__ q,
    u16* __restrict__ kk, u16* __restrict__ v, int b_fixed) {
  __shared__ __align__(16) u16 Asm[128 * 32];
  __shared__ __align__(16) u16 Bsm[128 * 32];
  const int bn = blockIdx.x;
  const int bm = blockIdx.y;
  const int tid = threadIdx.x;
  const int wave = tid >> 6, lane = tid & 63;
  const int col = lane & 15, quad = lane >> 4;
  int b, s0, hb;
  if (b_fixed < 0) { b = bm >> 4; s0 = (bm & 15) * 128; hb = b * 16; }
  else             { b = b_fixed; s0 = bm * 128;        hb = 0; }

  const int arow = tid >> 1;
  const int kseg = (tid & 1) * 16;
  const float* gA = inp + (size_t)((s0 + arow) * 4 + b) * 1024 + kseg;
  const float* gB = Wqkv + (size_t)(bn * 128 + arow) * 1024 + kseg;
  u16* lA = Asm + arow * 32 + kseg;
  u16* lB = Bsm + arow * 32 + kseg;
  const int wm = (wave >> 1) * 64, wn = (wave & 1) * 64;

  f32x4 acc[4][4];
#pragma unroll
  for (int i = 0; i < 4; ++i)
#pragma unroll
    for (int j = 0; j < 4; ++j) acc[i][j] = f32x4{0.f, 0.f, 0.f, 0.f};

  for (int k0 = 0; k0 < 1024; k0 += 32) {
    float4 av[4], bv[4];
#pragma unroll
    for (int u = 0; u < 4; ++u) av[u] = *(const float4*)(gA + k0 + u * 4);
#pragma unroll
    for (int u = 0; u < 4; ++u) bv[u] = *(const float4*)(gB + k0 + u * 4);
    __syncthreads();
    cvt16_store(av, lA);
    cvt16_store(bv, lB);
    __syncthreads();
    bf16x8 af[4], bfr[4];
#pragma unroll
    for (int i = 0; i < 4; ++i)
      af[i] = *(const bf16x8*)(Asm + (wm + i * 16 + col) * 32 + quad * 8);
#pragma unroll
    for (int j = 0; j < 4; ++j)
      bfr[j] = *(const bf16x8*)(Bsm + (wn + j * 16 + col) * 32 + quad * 8);
#pragma unroll
    for (int i = 0; i < 4; ++i)
#pragma unroll
      for (int j = 0; j < 4; ++j)
        acc[i][j] = __builtin_amdgcn_mfma_f32_16x16x32_bf16(af[i], bfr[j], acc[i][j], 0, 0, 0);
  }

  const float QS = 0.125f * 1.44269504088896f;
#pragma unroll
  for (int j = 0; j < 4; ++j) {
    const int n = bn * 128 + wn + j * 16 + col;
    const float bias = bqkv[n];
    const int region = n >> 10;
    const int hh = (n >> 6) & 15;
    const int dh = n & 63;
    if (region == 2) {
      const size_t baseT = ((size_t)(hb + hh) * 64 + dh) * 2048;
#pragma unroll
      for (int i = 0; i < 4; ++i) {
        const int srow = s0 + wm + i * 16 + quad * 4;
#pragma unroll
        for (int r = 0; r < 4; ++r)
          v[baseT + srow + r] = f2b(acc[i][j][r] + bias);
      }
    } else {
      u16* outp = (region == 0) ? q : kk;
      const float mult = (region == 0) ? QS : 1.0f;
      const size_t base = ((size_t)(hb + hh) * 2048) * 64 + dh;
#pragma unroll
      for (int i = 0; i < 4; ++i) {
        const int srow = s0 + wm + i * 16 + quad * 4;
#pragma unroll
        for (int r = 0; r < 4; ++r)
          outp[base + (size_t)(srow + r) * 64] = f2b((acc[i][j][r] + bias) * mult);
      }
    }
  }
}

// ---------------- K2: flash attention, VALU-trimmed (defer-max + LDS mask) ----------------
// R12: R11 post-mortem: dur pinned ~137us across R8/R10/R11 while MfmaUtil
// rose 21->32.5 and VALUBusy 52->56 -> we finally hit the combined SIMD
// issue wall (VALU+MFMA ~88%). Now cutting VALU ops should move dur:
// (1) mask bias precomputed once into LDS Msmf (8KB, broadcast ds_read -
//     R8 pattern, 0 conflicts) - removes 4 global loads + 16 cndmask/iter.
// (2) defer-max (T13, EXACT form): resc = __any(tm > mrun) per qt. When
//     false, mnew==mrun and alpha==1 identically -> skip alpha-exp, the 8
//     ar-broadcast bpermutes, and the 32 o-rescale muls (hoisted out of PV
//     into a conditional pre-pass). Bit-exact; for random scores only
//     ~sum(1/kt)~4 of 32 iters rescale.
// Keeps: in-register P via 16x16x16 PV (R11), XCD swizzle (R9), K/V double
// buffer + 1 barrier/iter (R10), setprio. LDS 40KB -> still 4 blocks/CU.
__global__ __launch_bounds__(256, 4) void k_attn(
    const u16* __restrict__ q, const u16* __restrict__ k,
    const u16* __restrict__ v, const int* __restrict__ mask,
    u16* __restrict__ attn, int b_fixed) {
  __shared__ __align__(16) float Msmf[2048];     // 8KB mask bias row
  __shared__ __align__(16) u16 Ksm[2][64 * 64];  // 16KB double-buffered
  __shared__ __align__(16) u16 Vsm[2][64 * 64];  // 16KB double-buffered
  const int bid = blockIdx.x;
  const int tid = threadIdx.x, wave = tid >> 6, lane = tid & 63;
  const int col = lane & 15, quad = lane >> 4;
  int qblk, h, b, hb;
  if (b_fixed < 0) {
    // work id w: group w>>4 = (b,h); all 16 q-blocks of a group on one XCD
    const int w = ((bid & 7) << 7) | (bid >> 3);
    qblk = w & 15; h = (w >> 4) & 15; b = w >> 8; hb = b * 16 + h;
  } else {
    qblk = bid & 15; h = bid >> 4; b = b_fixed; hb = h;
  }
  const size_t bh = (size_t)hb * 2048 * 64;

  {  // stage mask row b (2048 int32) into Msmf, convert in place to bias
    const int c = wave * 2;
    gld16(mask + b * 2048 + c * 256 + lane * 4, (char*)Msmf + c * 1024);
    gld16(mask + b * 2048 + (c + 1) * 256 + lane * 4, (char*)Msmf + (c + 1) * 1024);
  }
  __builtin_amdgcn_s_waitcnt(0);
  __syncthreads();
  for (int i = tid; i < 2048; i += 256) {
    const int mi = ((const int*)Msmf)[i];
    Msmf[i] = mi ? -1e30f : 0.f;
  }

  bf16x8 qf[2][2];
#pragma unroll
  for (int qt = 0; qt < 2; ++qt)
#pragma unroll
    for (int c = 0; c < 2; ++c)
      qf[qt][c] = *(const bf16x8*)(q + bh +
                   (size_t)(qblk * 128 + wave * 32 + qt * 16 + col) * 64 + c * 32 + quad * 8);

  const int r8 = lane >> 3, chn = lane & 7;
  const int g = chn ^ r8;
  const int swz = col & 7;

  // cooperative stage of one 64-key K/V tile into buffer `buf`
  auto STAGE = [&](int buf, int kt) {
#pragma unroll
    for (int s = 0; s < 2; ++s) {
      const int row = (wave * 2 + s) * 8 + r8;
      gld16(k + bh + (size_t)(kt * 64 + row) * 64 + g * 8,
            (char*)Ksm[buf] + (wave * 2 + s) * 1024);
      gld16(v + bh + (size_t)row * 2048 + kt * 64 + g * 8,
            (char*)Vsm[buf] + (wave * 2 + s) * 1024);
    }
  };

  f32x4 o[2][4];
#pragma unroll
  for (int qt = 0; qt < 2; ++qt)
#pragma unroll
    for (int n = 0; n < 4; ++n) o[qt][n] = f32x4{0.f, 0.f, 0.f, 0.f};
  float mrun[2] = {-1e30f, -1e30f}, lrun[2] = {0.f, 0.f};

  // prologue: stage kt=0 into buffer 0 (barrier also covers Msmf convert)
  STAGE(0, 0);
  asm volatile("s_waitcnt vmcnt(0)" ::: "memory");
  __syncthreads();

  int cur = 0;
  for (int kt = 0; kt < 32; ++kt) {
    if (kt < 31) STAGE(cur ^ 1, kt + 1);

    // ---- QK: mt-outer, mask bias (from LDS, broadcast) as C-init ----
    f32x4 sc[2][4];  // [qt][mt]
    __builtin_amdgcn_s_setprio(1);
#pragma unroll
    for (int mt = 0; mt < 4; ++mt) {
      const bf16x8 ka0 = *(const bf16x8*)((const char*)Ksm[cur] +
          (mt * 16 + col) * 128 + (quad ^ swz) * 16);
      const bf16x8 ka1 = *(const bf16x8*)((const char*)Ksm[cur] +
          (mt * 16 + col) * 128 + ((4 + quad) ^ swz) * 16);
      const float4 mbv = *(const float4*)(Msmf + kt * 64 + mt * 16 + quad * 4);
#pragma unroll
      for (int qt = 0; qt < 2; ++qt) {
        f32x4 z = {mbv.x, mbv.y, mbv.z, mbv.w};
        z = __builtin_amdgcn_mfma_f32_16x16x32_bf16(ka0, qf[qt][0], z, 0, 0, 0);
        sc[qt][mt] = __builtin_amdgcn_mfma_f32_16x16x32_bf16(ka1, qf[qt][1], z, 0, 0, 0);
      }
    }
    __builtin_amdgcn_s_setprio(0);

    // ---- online softmax with defer-max; P packed in-register ----
    float alpha[2];
    int resc[2];
    bf16x4s pa[2][4];  // [qt][mt]: P[q=col][key=quad*4+j] -- matches sc layout
#pragma unroll
    for (int qt = 0; qt < 2; ++qt) {
      float tm = fmaxf(fmaxf(sc[qt][0][0], sc[qt][0][1]),
                       fmaxf(sc[qt][0][2], sc[qt][0][3]));
#pragma unroll
      for (int mt = 1; mt < 4; ++mt)
#pragma unroll
        for (int r = 0; r < 4; ++r) tm = fmaxf(tm, sc[qt][mt][r]);
      tm = fmaxf(tm, __shfl_xor(tm, 16, 64));
      tm = fmaxf(tm, __shfl_xor(tm, 32, 64));
      resc[qt] = __any(tm > mrun[qt]);
      if (resc[qt]) {  // wave-uniform branch
        const float mnew = fmaxf(mrun[qt], tm);
        alpha[qt] = __builtin_amdgcn_exp2f(mrun[qt] - mnew);
        mrun[qt] = mnew;
      } else {
        alpha[qt] = 1.0f;  // exact: mnew == mrun
      }
      float sum = 0.f;
#pragma unroll
      for (int mt = 0; mt < 4; ++mt)
#pragma unroll
        for (int r = 0; r < 4; ++r) {
          sc[qt][mt][r] = __builtin_amdgcn_exp2f(sc[qt][mt][r] - mrun[qt]);
          sum += sc[qt][mt][r];
        }
      sum += __shfl_xor(sum, 16, 64);
      sum += __shfl_xor(sum, 32, 64);
      lrun[qt] = lrun[qt] * alpha[qt] + sum;
#pragma unroll
      for (int mt = 0; mt < 4; ++mt) {
        uint2 w;
        w.x = pk2(sc[qt][mt][0], sc[qt][mt][1]);
        w.y = pk2(sc[qt][mt][2], sc[qt][mt][3]);
        pa[qt][mt] = __builtin_bit_cast(bf16x4s, w);
      }
    }

    // ---- conditional o-rescale (skipped in ~90% of iterations) ----
    if (resc[0] | resc[1]) {
      float ar[2][4];
#pragma unroll
      for (int qt = 0; qt < 2; ++qt)
#pragma unroll
        for (int r = 0; r < 4; ++r) ar[qt][r] = __shfl(alpha[qt], quad * 4 + r, 64);
#pragma unroll
      for (int qt = 0; qt < 2; ++qt)
#pragma unroll
        for (int nt = 0; nt < 4; ++nt)
#pragma unroll
          for (int r = 0; r < 4; ++r) o[qt][nt][r] *= ar[qt][r];
    }

    // ---- PV: K=16 MFMAs, V fragments as ds_read_b64 (keys quad*4..+3) ----
    __builtin_amdgcn_s_setprio(1);
#pragma unroll
    for (int nt = 0; nt < 4; ++nt) {
      bf16x4s vb[4];
#pragma unroll
      for (int mt = 0; mt < 4; ++mt) {
        // Vsm row = dh = nt*16+col; stored 16B-chunk p holds keys (p^swz)*8
        const uint2 raw = *(const uint2*)((const char*)Vsm[cur] +
            (nt * 16 + col) * 128 + (((mt * 2 + (quad >> 1)) ^ swz) << 4) +
            ((quad & 1) << 3));
        vb[mt] = __builtin_bit_cast(bf16x4s, raw);
      }
#pragma unroll
      for (int qt = 0; qt < 2; ++qt) {
        f32x4 t = o[qt][nt];
#pragma unroll
        for (int mt = 0; mt < 4; ++mt) t = mfma16(pa[qt][mt], vb[mt], t);
        o[qt][nt] = t;
      }
    }
    __builtin_amdgcn_s_setprio(0);

    // next-tile loads were issued ~one full compute phase ago
    asm volatile("s_waitcnt vmcnt(0)" ::: "memory");
    __syncthreads();
    cur ^= 1;
  }

  const int arow0 = (b_fixed < 0) ? b * 2048 : 0;
#pragma unroll
  for (int qt = 0; qt < 2; ++qt) {
    float inv[4];
#pragma unroll
    for (int r = 0; r < 4; ++r) {
      const float lr = __shfl(lrun[qt], quad * 4 + r, 64);
      inv[r] = 1.0f / lr;
    }
#pragma unroll
    for (int n = 0; n < 4; ++n)
#pragma unroll
      for (int r = 0; r < 4; ++r) {
        const int srow = qblk * 128 + wave * 32 + qt * 16 + quad * 4 + r;
        const size_t idx = ((size_t)(arow0 + srow)) * 1024 + h * 64 + n * 16 + col;
        attn[idx] = f2b(o[qt][n][r] * inv[r]);
      }
  }
}

// ---------------- K3a: output projection, all-bf16 staging ----------------
__global__ __launch_bounds__(256, 2) void k_proj_a(
    const u16* __restrict__ attn, const u16* __restrict__ wb,
    const float* __restrict__ bproj, float* __restrict__ out) {
  __shared__ __align__(16) u16 Asm[128 * 32];
  __shared__ __align__(16) u16 Bsm[128 * 32];
  const int bn = blockIdx.x;  // 0..7
  const int bm = blockIdx.y;  // 0..63
  const int tid = threadIdx.x;
  const int wave = tid >> 6, lane = tid & 63;
  const int col = lane & 15, quad = lane >> 4;
  const int b = bm >> 4;
  const int s0 = (bm & 15) * 128;
  const int c0 = wave * 2;
  const int srow0 = c0 * 16 + (lane >> 2);
  const int kc = (lane & 3) * 8;
  const u16* gA0 = attn + (size_t)(bm * 128 + srow0) * 1024 + kc;
  const u16* gA1 = attn + (size_t)(bm * 128 + srow0 + 16) * 1024 + kc;
  const u16* gB0 = wb + (size_t)(bn * 128 + srow0) * 1024 + kc;
  const u16* gB1 = wb + (size_t)(bn * 128 + srow0 + 16) * 1024 + kc;
  u16* lA0 = Asm + c0 * 512;
  u16* lA1 = Asm + c0 * 512 + 512;
  u16* lB0 = Bsm + c0 * 512;
  u16* lB1 = Bsm + c0 * 512 + 512;
  const int wm = (wave >> 1) * 64, wn = (wave & 1) * 64;

  f32x4 acc[4][4];
#pragma unroll
  for (int i = 0; i < 4; ++i)
#pragma unroll
    for (int j = 0; j < 4; ++j) acc[i][j] = f32x4{0.f, 0.f, 0.f, 0.f};

  for (int k0 = 0; k0 < 1024; k0 += 32) {
    __syncthreads();
    gld16(gA0 + k0, lA0);
    gld16(gA1 + k0, lA1);
    gld16(gB0 + k0, lB0);
    gld16(gB1 + k0, lB1);
    __builtin_amdgcn_s_waitcnt(0);
    __syncthreads();
    bf16x8 af[4], bfr[4];
#pragma unroll
    for (int i = 0; i < 4; ++i)
      af[i] = *(const bf16x8*)(Asm + (wm + i * 16 + col) * 32 + quad * 8);
#pragma unroll
    for (int j = 0; j < 4; ++j)
      bfr[j] = *(const bf16x8*)(Bsm + (wn + j * 16 + col) * 32 + quad * 8);
#pragma unroll
    for (int i = 0; i < 4; ++i)
#pragma unroll
      for (int j = 0; j < 4; ++j)
        acc[i][j] = __builtin_amdgcn_mfma_f32_16x16x32_bf16(af[i], bfr[j], acc[i][j], 0, 0, 0);
  }

#pragma unroll
  for (int j = 0; j < 4; ++j) {
    const int n = bn * 128 + wn + j * 16 + col;
    const float bias = bproj[n];
#pragma unroll
    for (int i = 0; i < 4; ++i) {
      const int srow = s0 + wm + i * 16 + quad * 4;
#pragma unroll
      for (int r = 0; r < 4; ++r)
        out[(size_t)((srow + r) * 4 + b) * 1024 + n] = acc[i][j][r] + bias;
    }
  }
}

// ---------------- K3b: output projection, inline-convert B (fallback) ----------------
__global__ __launch_bounds__(256, 2) void k_proj_f32(
    const u16* __restrict__ attn, const float* __restrict__ Wproj,
    const float* __restrict__ bproj, float* __restrict__ out, int b_fixed) {
  __shared__ __align__(16) u16 Asm[128 * 32];
  __shared__ __align__(16) u16 Bsm[128 * 32];
  const int bn = blockIdx.x;
  const int bm = blockIdx.y;
  const int tid = threadIdx.x;
  const int wave = tid >> 6, lane = tid & 63;
  const int col = lane & 15, quad = lane >> 4;
  int b, s0;
  if (b_fixed < 0) { b = bm >> 4; s0 = (bm & 15) * 128; }
  else             { b = b_fixed; s0 = bm * 128; }

  const int c0 = wave * 2;
  const int srow0 = c0 * 16 + (lane >> 2);
  const int kc = (lane & 3) * 8;
  const u16* gA0 = attn + (size_t)(bm * 128 + srow0) * 1024 + kc;
  const u16* gA1 = attn + (size_t)(bm * 128 + srow0 + 16) * 1024 + kc;
  u16* lA0 = Asm + c0 * 512;
  u16* lA1 = Asm + c0 * 512 + 512;
  const int brow = tid >> 1;
  const int kseg = (tid & 1) * 16;
  const float* gB = Wproj + (size_t)(bn * 128 + brow) * 1024 + kseg;
  u16* lB = Bsm + brow * 32 + kseg;
  const int wm = (wave >> 1) * 64, wn = (wave & 1) * 64;

  f32x4 acc[4][4];
#pragma unroll
  for (int i = 0; i < 4; ++i)
#pragma unroll
    for (int j = 0; j < 4; ++j) acc[i][j] = f32x4{0.f, 0.f, 0.f, 0.f};

  for (int k0 = 0; k0 < 1024; k0 += 32) {
    float4 bv[4];
#pragma unroll
    for (int u = 0; u < 4; ++u) bv[u] = *(const float4*)(gB + k0 + u * 4);
    __syncthreads();
    gld16(gA0 + k0, lA0);
    gld16(gA1 + k0, lA1);
    cvt16_store(bv, lB);
    __builtin_amdgcn_s_waitcnt(0);
    __syncthreads();
    bf16x8 af[4], bfr[4];
#pragma unroll
    for (int i = 0; i < 4; ++i)
      af[i] = *(const bf16x8*)(Asm + (wm + i * 16 + col) * 32 + quad * 8);
#pragma unroll
    for (int j = 0; j < 4; ++j)
      bfr[j] = *(const bf16x8*)(Bsm + (wn + j * 16 + col) * 32 + quad * 8);
#pragma unroll
    for (int i = 0; i < 4; ++i)
#pragma unroll
      for (int j = 0; j < 4; ++j)
        acc[i][j] = __builtin_amdgcn_mfma_f32_16x16x32_bf16(af[i], bfr[j], acc[i][j], 0, 0, 0);
  }

#pragma unroll
  for (int j = 0; j < 4; ++j) {
    const int n = bn * 128 + wn + j * 16 + col;
    const float bias = bproj[n];
#pragma unroll
    for (int i = 0; i < 4; ++i) {
      const int srow = s0 + wm + i * 16 + quad * 4;
#pragma unroll
      for (int r = 0; r < 4; ++r)
        out[(size_t)((srow + r) * 4 + b) * 1024 + n] = acc[i][j][r] + bias;
    }
  }
}

extern "C" void kernel_launch(void* const* d_in, const int* in_sizes, int n_in,
                              void* d_out, int out_size, void* d_ws, size_t ws_size,
                              hipStream_t stream) {
  const float* inp = (const float*)d_in[0];
  const int* mask = (const int*)d_in[1];
  const float* Wqkv = (const float*)d_in[2];
  const float* bqkv = (const float*)d_in[3];
  const float* Wproj = (const float*)d_in[4];
  const float* bproj = (const float*)d_in[5];
  float* out = (float*)d_out;

  const size_t FULLSZ = (size_t)BATCH * NHEAD * SEQ * DHEAD;  // 8388608 elems
  const size_t WQKV_E = (size_t)3 * DIM * DIM;                // 3145728
  const size_t WPROJ_E = (size_t)DIM * DIM;                   // 1048576
  const size_t pathA_bytes = (4 * FULLSZ + WQKV_E + WPROJ_E) * sizeof(u16);  // 75.5 MB

  if (ws_size >= pathA_bytes) {
    // Path A: convert-once + all-async-bf16 GEMMs.
    u16* q = (u16*)d_ws;
    u16* kk = q + FULLSZ;
    u16* v = kk + FULLSZ;
    u16* xb = v + FULLSZ;      // converted inp; later overwritten as attn buffer
    u16* attn = xb;            // alias — k_attn writes after k_qkv_a finished reading
    u16* wqkvb = xb + FULLSZ;
    u16* wprojb = wqkvb + WQKV_E;
    k_cvt<<<dim3(12288), 256, 0, stream>>>(inp, Wqkv, Wproj, xb, wqkvb, wprojb);
    k_qkv_a<<<dim3(24, 64), 256, 0, stream>>>(xb, wqkvb, bqkv, q, kk, v);
    k_attn<<<dim3(1024), 256, 0, stream>>>(q, kk, v, mask, attn, -1);
    k_proj_a<<<dim3(8, 64), 256, 0, stream>>>(attn, wprojb, bproj, out);
  } else if (ws_size >= 4 * FULLSZ * sizeof(u16)) {
    // Path B: proven R5 pipeline (inline f32 convert).
    u16* q = (u16*)d_ws;
    u16* kk = q + FULLSZ;
    u16* v = kk + FULLSZ;
    u16* attn = v + FULLSZ;
    k_qkv_f32<<<dim3(24, 64), 256, 0, stream>>>(inp, Wqkv, bqkv, q, kk, v, -1);
    k_attn<<<dim3(1024), 256, 0, stream>>>(q, kk, v, mask, attn, -1);
    k_proj_f32<<<dim3(8, 64), 256, 0, stream>>>(attn, Wproj, bproj, out, -1);
  } else {
    // Path C: per-batch pipeline, 16 MiB workspace.
    const size_t BSZ = (size_t)NHEAD * SEQ * DHEAD;
    u16* q = (u16*)d_ws;
    u16* kk = q + BSZ;
    u16* v = kk + BSZ;
    u16* attn = v + BSZ;
    for (int b = 0; b < BATCH; ++b) {
      k_qkv_f32<<<dim3(24, 16), 256, 0, stream>>>(inp, Wqkv, bqkv, q, kk, v, b);
      k_attn<<<dim3(256), 256, 0, stream>>>(q, kk, v, mask, attn, b);
      k_proj_f32<<<dim3(8, 16), 256, 0, stream>>>(attn, Wproj, bproj, out, b);
    }
  }
}

// Round 7
// 305.812 us; speedup vs baseline: 1.0239x; 1.0044x over previous
//
#include <hip/hip_runtime.h>

#define SEQ 2048
#define BATCH 4
#define DIM 1024
#define NHEAD 16
#define DHEAD 64

typedef __bf16 bf16;
typedef __bf16 bf16x8 __attribute__((ext_vector_type(8)));
typedef short bf16x4s __attribute__((ext_vector_type(4)));
typedef float f32x4 __attribute__((ext_vector_type(4)));
typedef unsigned int u32x4 __attribute__((ext_vector_type(4)));
typedef unsigned short u16;
typedef unsigned int u32;

__device__ __forceinline__ void gld16(const void* g, void* l) {
  __builtin_amdgcn_global_load_lds((__attribute__((address_space(1))) void*)(void*)g,
                                   (__attribute__((address_space(3))) void*)l, 16, 0, 0);
}

__device__ __forceinline__ u16 f2b(float f) {  // fp32 -> bf16 bits, RNE
  u32 u = __builtin_bit_cast(u32, f);
  u32 r = (u + 0x7FFFu + ((u >> 16) & 1u)) >> 16;
  return (u16)r;
}

// pack two f32 -> (bf16(f1)<<16)|bf16(f0), round-half-up (==RNE except exact ties)
__device__ __forceinline__ u32 pk2(float f0, float f1) {
  const u32 a = __builtin_bit_cast(u32, f1) + 0x8000u;
  const u32 b = __builtin_bit_cast(u32, f0) + 0x8000u;
  return __builtin_amdgcn_perm(a, b, 0x07060302u);
}

// K=16 bf16 MFMA: A/B = 4 bf16 (2 VGPR), layout A[m=lane&15][k=quad*4+j]
__device__ __forceinline__ f32x4 mfma16(bf16x4s a, bf16x4s b, f32x4 c) {
#if __has_builtin(__builtin_amdgcn_mfma_f32_16x16x16bf16_1k)
  return __builtin_amdgcn_mfma_f32_16x16x16bf16_1k(a, b, c, 0, 0, 0);
#else
  asm volatile("v_mfma_f32_16x16x16_bf16 %0, %1, %2, %0"
               : "+v"(c) : "v"(a), "v"(b));
  return c;
#endif
}

__device__ __forceinline__ void cvt16_store(const float4 v[4], u16* dst) {
  union { u16 h[16]; uint4 q[2]; } pk;
#pragma unroll
  for (int j = 0; j < 4; ++j) {
    pk.h[j * 4 + 0] = f2b(v[j].x);
    pk.h[j * 4 + 1] = f2b(v[j].y);
    pk.h[j * 4 + 2] = f2b(v[j].z);
    pk.h[j * 4 + 3] = f2b(v[j].w);
  }
  ((uint4*)dst)[0] = pk.q[0];
  ((uint4*)dst)[1] = pk.q[1];
}

// ---------------- K0: one-shot f32 -> bf16 conversion ----------------
__global__ __launch_bounds__(256) void k_cvt(
    const float* __restrict__ inp, const float* __restrict__ wqkv,
    const float* __restrict__ wproj, u16* __restrict__ xb,
    u16* __restrict__ wqkvb, u16* __restrict__ wprojb) {
  const int idx = blockIdx.x * 256 + threadIdx.x;
  const float4* src;
  u16* dst;
  int off;
  if (idx < 2097152)      { src = (const float4*)inp;   dst = xb;     off = idx; }
  else if (idx < 2883584) { src = (const float4*)wqkv;  dst = wqkvb;  off = idx - 2097152; }
  else                    { src = (const float4*)wproj; dst = wprojb; off = idx - 2883584; }
  const float4 v = src[off];
  union { u16 h[4]; uint2 q; } pk;
  pk.h[0] = f2b(v.x); pk.h[1] = f2b(v.y); pk.h[2] = f2b(v.z); pk.h[3] = f2b(v.w);
  *(uint2*)(dst + (size_t)off * 4) = pk.q;
}

// ---------------- K1a: QKV projection, all-bf16, async staging ----------------
__global__ __launch_bounds__(256, 2) void k_qkv_a(
    const u16* __restrict__ xb, const u16* __restrict__ wb,
    const float* __restrict__ bqkv, u16* __restrict__ q,
    u16* __restrict__ kk, u16* __restrict__ v) {
  __shared__ __align__(16) u16 Asm[128 * 32];
  __shared__ __align__(16) u16 Bsm[128 * 32];
  const int bn = blockIdx.x;   // 0..23
  const int bm = blockIdx.y;   // 0..63
  const int tid = threadIdx.x;
  const int wave = tid >> 6, lane = tid & 63;
  const int col = lane & 15, quad = lane >> 4;
  const int b = bm >> 4;
  const int s0 = (bm & 15) * 128;
  const int c0 = wave * 2;
  const int srow0 = c0 * 16 + (lane >> 2);
  const int kc = (lane & 3) * 8;
  const u16* gA0 = xb + (size_t)((s0 + srow0) * 4 + b) * 1024 + kc;
  const u16* gA1 = xb + (size_t)((s0 + srow0 + 16) * 4 + b) * 1024 + kc;
  const u16* gB0 = wb + (size_t)(bn * 128 + srow0) * 1024 + kc;
  const u16* gB1 = wb + (size_t)(bn * 128 + srow0 + 16) * 1024 + kc;
  u16* lA0 = Asm + c0 * 512;
  u16* lA1 = Asm + c0 * 512 + 512;
  u16* lB0 = Bsm + c0 * 512;
  u16* lB1 = Bsm + c0 * 512 + 512;
  const int wm = (wave >> 1) * 64, wn = (wave & 1) * 64;

  f32x4 acc[4][4];
#pragma unroll
  for (int i = 0; i < 4; ++i)
#pragma unroll
    for (int j = 0; j < 4; ++j) acc[i][j] = f32x4{0.f, 0.f, 0.f, 0.f};

  for (int k0 = 0; k0 < 1024; k0 += 32) {
    __syncthreads();
    gld16(gA0 + k0, lA0);
    gld16(gA1 + k0, lA1);
    gld16(gB0 + k0, lB0);
    gld16(gB1 + k0, lB1);
    __builtin_amdgcn_s_waitcnt(0);
    __syncthreads();
    bf16x8 af[4], bfr[4];
#pragma unroll
    for (int i = 0; i < 4; ++i)
      af[i] = *(const bf16x8*)(Asm + (wm + i * 16 + col) * 32 + quad * 8);
#pragma unroll
    for (int j = 0; j < 4; ++j)
      bfr[j] = *(const bf16x8*)(Bsm + (wn + j * 16 + col) * 32 + quad * 8);
#pragma unroll
    for (int i = 0; i < 4; ++i)
#pragma unroll
      for (int j = 0; j < 4; ++j)
        acc[i][j] = __builtin_amdgcn_mfma_f32_16x16x32_bf16(af[i], bfr[j], acc[i][j], 0, 0, 0);
  }

  const float QS = 0.125f * 1.44269504088896f;  // SCALE * log2(e)
#pragma unroll
  for (int j = 0; j < 4; ++j) {
    const int n = bn * 128 + wn + j * 16 + col;
    const float bias = bqkv[n];
    const int region = n >> 10;  // 0=q 1=k 2=v
    const int hh = (n >> 6) & 15;
    const int dh = n & 63;
    if (region == 2) {  // V transposed: [B,H,DH,S]
      const size_t baseT = ((size_t)(b * 16 + hh) * 64 + dh) * 2048;
#pragma unroll
      for (int i = 0; i < 4; ++i) {
        const int srow = s0 + wm + i * 16 + quad * 4;
#pragma unroll
        for (int r = 0; r < 4; ++r)
          v[baseT + srow + r] = f2b(acc[i][j][r] + bias);
      }
    } else {
      u16* outp = (region == 0) ? q : kk;
      const float mult = (region == 0) ? QS : 1.0f;
      const size_t base = ((size_t)(b * 16 + hh) * 2048) * 64 + dh;
#pragma unroll
      for (int i = 0; i < 4; ++i) {
        const int srow = s0 + wm + i * 16 + quad * 4;
#pragma unroll
        for (int r = 0; r < 4; ++r)
          outp[base + (size_t)(srow + r) * 64] = f2b((acc[i][j][r] + bias) * mult);
      }
    }
  }
}

// ---------------- K1b: QKV projection, f32-inline-convert (fallback) ----------------
__global__ __launch_bounds__(256, 2) void k_qkv_f32(
    const float* __restrict__ inp, const float* __restrict__ Wqkv,
    const float* __restrict__ bqkv, u16* __restrict__ q,
    u16* __restrict__ kk, u16* __restrict__ v, int b_fixed) {
  __shared__ __align__(16) u16 Asm[128 * 32];
  __shared__ __align__(16) u16 Bsm[128 * 32];
  const int bn = blockIdx.x;
  const int bm = blockIdx.y;
  const int tid = threadIdx.x;
  const int wave = tid >> 6, lane = tid & 63;
  const int col = lane & 15, quad = lane >> 4;
  int b, s0, hb;
  if (b_fixed < 0) { b = bm >> 4; s0 = (bm & 15) * 128; hb = b * 16; }
  else             { b = b_fixed; s0 = bm * 128;        hb = 0; }

  const int arow = tid >> 1;
  const int kseg = (tid & 1) * 16;
  const float* gA = inp + (size_t)((s0 + arow) * 4 + b) * 1024 + kseg;
  const float* gB = Wqkv + (size_t)(bn * 128 + arow) * 1024 + kseg;
  u16* lA = Asm + arow * 32 + kseg;
  u16* lB = Bsm + arow * 32 + kseg;
  const int wm = (wave >> 1) * 64, wn = (wave & 1) * 64;

  f32x4 acc[4][4];
#pragma unroll
  for (int i = 0; i < 4; ++i)
#pragma unroll
    for (int j = 0; j < 4; ++j) acc[i][j] = f32x4{0.f, 0.f, 0.f, 0.f};

  for (int k0 = 0; k0 < 1024; k0 += 32) {
    float4 av[4], bv[4];
#pragma unroll
    for (int u = 0; u < 4; ++u) av[u] = *(const float4*)(gA + k0 + u * 4);
#pragma unroll
    for (int u = 0; u < 4; ++u) bv[u] = *(const float4*)(gB + k0 + u * 4);
    __syncthreads();
    cvt16_store(av, lA);
    cvt16_store(bv, lB);
    __syncthreads();
    bf16x8 af[4], bfr[4];
#pragma unroll
    for (int i = 0; i < 4; ++i)
      af[i] = *(const bf16x8*)(Asm + (wm + i * 16 + col) * 32 + quad * 8);
#pragma unroll
    for (int j = 0; j < 4; ++j)
      bfr[j] = *(const bf16x8*)(Bsm + (wn + j * 16 + col) * 32 + quad * 8);
#pragma unroll
    for (int i = 0; i < 4; ++i)
#pragma unroll
      for (int j = 0; j < 4; ++j)
        acc[i][j] = __builtin_amdgcn_mfma_f32_16x16x32_bf16(af[i], bfr[j], acc[i][j], 0, 0, 0);
  }

  const float QS = 0.125f * 1.44269504088896f;
#pragma unroll
  for (int j = 0; j < 4; ++j) {
    const int n = bn * 128 + wn + j * 16 + col;
    const float bias = bqkv[n];
    const int region = n >> 10;
    const int hh = (n >> 6) & 15;
    const int dh = n & 63;
    if (region == 2) {
      const size_t baseT = ((size_t)(hb + hh) * 64 + dh) * 2048;
#pragma unroll
      for (int i = 0; i < 4; ++i) {
        const int srow = s0 + wm + i * 16 + quad * 4;
#pragma unroll
        for (int r = 0; r < 4; ++r)
          v[baseT + srow + r] = f2b(acc[i][j][r] + bias);
      }
    } else {
      u16* outp = (region == 0) ? q : kk;
      const float mult = (region == 0) ? QS : 1.0f;
      const size_t base = ((size_t)(hb + hh) * 2048) * 64 + dh;
#pragma unroll
      for (int i = 0; i < 4; ++i) {
        const int srow = s0 + wm + i * 16 + quad * 4;
#pragma unroll
        for (int r = 0; r < 4; ++r)
          outp[base + (size_t)(srow + r) * 64] = f2b((acc[i][j][r] + bias) * mult);
      }
    }
  }
}

// ---------------- K2: flash attention, MFMA row-sum (pk2 pack retained) ----------------
// R15: R14 post-mortem (FAILED absmax 0.29): bundled cvt_pk + MFMA-rowsum.
// Row-sum is layout-proof (B=ones => D[m][n]=sum_k A[m][k] under ANY B
// fragment layout; D-row mapping is the same one R12's PV output already
// validated). cvt_pk's builtin/asm lo-hi semantics are the unverified piece
// -> dropped, pk2 (R12-proven, bit-identical pack) retained.
// This round = R12 + MFMA row-sum ONLY:
//   lacc[qt] += P.ones via 8 mfma16/iter; removes 32 v_add + 4 shfl_xor
//   (serial chain) + lrun FMA per iter + 8 epilogue broadcast-shfls
//   (inv[r]=1/lacc[r] direct). Denominator sums bf16-quantized P =
//   consistent with PV numerator.
// Keeps: defer-max + LDS mask bias (R12), in-register P via 16x16x16 PV
// (R11), XCD swizzle (R9), K/V double-buffer + 1 barrier/iter (R10), setprio.
__global__ __launch_bounds__(256, 4) void k_attn(
    const u16* __restrict__ q, const u16* __restrict__ k,
    const u16* __restrict__ v, const int* __restrict__ mask,
    u16* __restrict__ attn, int b_fixed) {
  __shared__ __align__(16) float Msmf[2048];     // 8KB mask bias row
  __shared__ __align__(16) u16 Ksm[2][64 * 64];  // 16KB double-buffered
  __shared__ __align__(16) u16 Vsm[2][64 * 64];  // 16KB double-buffered
  const int bid = blockIdx.x;
  const int tid = threadIdx.x, wave = tid >> 6, lane = tid & 63;
  const int col = lane & 15, quad = lane >> 4;
  int qblk, h, b, hb;
  if (b_fixed < 0) {
    // work id w: group w>>4 = (b,h); all 16 q-blocks of a group on one XCD
    const int w = ((bid & 7) << 7) | (bid >> 3);
    qblk = w & 15; h = (w >> 4) & 15; b = w >> 8; hb = b * 16 + h;
  } else {
    qblk = bid & 15; h = bid >> 4; b = b_fixed; hb = h;
  }
  const size_t bh = (size_t)hb * 2048 * 64;

  {  // stage mask row b (2048 int32) into Msmf, convert in place to bias
    const int c = wave * 2;
    gld16(mask + b * 2048 + c * 256 + lane * 4, (char*)Msmf + c * 1024);
    gld16(mask + b * 2048 + (c + 1) * 256 + lane * 4, (char*)Msmf + (c + 1) * 1024);
  }
  __builtin_amdgcn_s_waitcnt(0);
  __syncthreads();
  for (int i = tid; i < 2048; i += 256) {
    const int mi = ((const int*)Msmf)[i];
    Msmf[i] = mi ? -1e30f : 0.f;
  }

  bf16x8 qf[2][2];
#pragma unroll
  for (int qt = 0; qt < 2; ++qt)
#pragma unroll
    for (int c = 0; c < 2; ++c)
      qf[qt][c] = *(const bf16x8*)(q + bh +
                   (size_t)(qblk * 128 + wave * 32 + qt * 16 + col) * 64 + c * 32 + quad * 8);

  const int r8 = lane >> 3, chn = lane & 7;
  const int g = chn ^ r8;
  const int swz = col & 7;

  // cooperative stage of one 64-key K/V tile into buffer `buf`
  auto STAGE = [&](int buf, int kt) {
#pragma unroll
    for (int s = 0; s < 2; ++s) {
      const int row = (wave * 2 + s) * 8 + r8;
      gld16(k + bh + (size_t)(kt * 64 + row) * 64 + g * 8,
            (char*)Ksm[buf] + (wave * 2 + s) * 1024);
      gld16(v + bh + (size_t)row * 2048 + kt * 64 + g * 8,
            (char*)Vsm[buf] + (wave * 2 + s) * 1024);
    }
  };

  f32x4 o[2][4];
#pragma unroll
  for (int qt = 0; qt < 2; ++qt)
#pragma unroll
    for (int n = 0; n < 4; ++n) o[qt][n] = f32x4{0.f, 0.f, 0.f, 0.f};
  f32x4 lacc[2] = {f32x4{0.f, 0.f, 0.f, 0.f}, f32x4{0.f, 0.f, 0.f, 0.f}};
  float mrun[2] = {-1e30f, -1e30f};
  const bf16x4s vones = {0x3F80, 0x3F80, 0x3F80, 0x3F80};  // bf16 1.0 x4

  // prologue: stage kt=0 into buffer 0 (barrier also covers Msmf convert)
  STAGE(0, 0);
  asm volatile("s_waitcnt vmcnt(0)" ::: "memory");
  __syncthreads();

  int cur = 0;
  for (int kt = 0; kt < 32; ++kt) {
    if (kt < 31) STAGE(cur ^ 1, kt + 1);

    // ---- QK: mt-outer, mask bias (from LDS, broadcast) as C-init ----
    f32x4 sc[2][4];  // [qt][mt]
    __builtin_amdgcn_s_setprio(1);
#pragma unroll
    for (int mt = 0; mt < 4; ++mt) {
      const bf16x8 ka0 = *(const bf16x8*)((const char*)Ksm[cur] +
          (mt * 16 + col) * 128 + (quad ^ swz) * 16);
      const bf16x8 ka1 = *(const bf16x8*)((const char*)Ksm[cur] +
          (mt * 16 + col) * 128 + ((4 + quad) ^ swz) * 16);
      const float4 mbv = *(const float4*)(Msmf + kt * 64 + mt * 16 + quad * 4);
#pragma unroll
      for (int qt = 0; qt < 2; ++qt) {
        f32x4 z = {mbv.x, mbv.y, mbv.z, mbv.w};
        z = __builtin_amdgcn_mfma_f32_16x16x32_bf16(ka0, qf[qt][0], z, 0, 0, 0);
        sc[qt][mt] = __builtin_amdgcn_mfma_f32_16x16x32_bf16(ka1, qf[qt][1], z, 0, 0, 0);
      }
    }
    __builtin_amdgcn_s_setprio(0);

    // ---- online softmax with defer-max; P packed in-register via pk2 ----
    float alpha[2];
    int resc[2];
    bf16x4s pa[2][4];  // [qt][mt]: P[q=col][key=quad*4+j] -- matches sc layout
#pragma unroll
    for (int qt = 0; qt < 2; ++qt) {
      float tm = fmaxf(fmaxf(sc[qt][0][0], sc[qt][0][1]),
                       fmaxf(sc[qt][0][2], sc[qt][0][3]));
#pragma unroll
      for (int mt = 1; mt < 4; ++mt)
#pragma unroll
        for (int r = 0; r < 4; ++r) tm = fmaxf(tm, sc[qt][mt][r]);
      tm = fmaxf(tm, __shfl_xor(tm, 16, 64));
      tm = fmaxf(tm, __shfl_xor(tm, 32, 64));
      resc[qt] = __any(tm > mrun[qt]);
      if (resc[qt]) {  // wave-uniform branch
        const float mnew = fmaxf(mrun[qt], tm);
        alpha[qt] = __builtin_amdgcn_exp2f(mrun[qt] - mnew);
        mrun[qt] = mnew;
      } else {
        alpha[qt] = 1.0f;  // exact: mnew == mrun
      }
#pragma unroll
      for (int mt = 0; mt < 4; ++mt) {
#pragma unroll
        for (int r = 0; r < 4; ++r)
          sc[qt][mt][r] = __builtin_amdgcn_exp2f(sc[qt][mt][r] - mrun[qt]);
        uint2 w;
        w.x = pk2(sc[qt][mt][0], sc[qt][mt][1]);
        w.y = pk2(sc[qt][mt][2], sc[qt][mt][3]);
        pa[qt][mt] = __builtin_bit_cast(bf16x4s, w);
      }
    }

    // ---- conditional o/l-rescale (skipped in most iterations) ----
    if (resc[0] | resc[1]) {
      float ar[2][4];
#pragma unroll
      for (int qt = 0; qt < 2; ++qt)
#pragma unroll
        for (int r = 0; r < 4; ++r) ar[qt][r] = __shfl(alpha[qt], quad * 4 + r, 64);
#pragma unroll
      for (int qt = 0; qt < 2; ++qt) {
#pragma unroll
        for (int nt = 0; nt < 4; ++nt)
#pragma unroll
          for (int r = 0; r < 4; ++r) o[qt][nt][r] *= ar[qt][r];
#pragma unroll
        for (int r = 0; r < 4; ++r) lacc[qt][r] *= ar[qt][r];
      }
    }

    // ---- PV: K=16 MFMAs, V fragments as ds_read_b64 (keys quad*4..+3) ----
    __builtin_amdgcn_s_setprio(1);
#pragma unroll
    for (int nt = 0; nt < 4; ++nt) {
      bf16x4s vb[4];
#pragma unroll
      for (int mt = 0; mt < 4; ++mt) {
        // Vsm row = dh = nt*16+col; stored 16B-chunk p holds keys (p^swz)*8
        const uint2 raw = *(const uint2*)((const char*)Vsm[cur] +
            (nt * 16 + col) * 128 + (((mt * 2 + (quad >> 1)) ^ swz) << 4) +
            ((quad & 1) << 3));
        vb[mt] = __builtin_bit_cast(bf16x4s, raw);
      }
#pragma unroll
      for (int qt = 0; qt < 2; ++qt) {
        f32x4 t = o[qt][nt];
#pragma unroll
        for (int mt = 0; mt < 4; ++mt) t = mfma16(pa[qt][mt], vb[mt], t);
        o[qt][nt] = t;
      }
    }
    // row-sum via MFMA: lacc[qt] += P . ones  (B=ones => layout-independent;
    // D-row mapping row=quad*4+r is the same one o's epilogue already uses)
#pragma unroll
    for (int qt = 0; qt < 2; ++qt)
#pragma unroll
      for (int mt = 0; mt < 4; ++mt)
        lacc[qt] = mfma16(pa[qt][mt], vones, lacc[qt]);
    __builtin_amdgcn_s_setprio(0);

    // next-tile loads were issued ~one full compute phase ago
    asm volatile("s_waitcnt vmcnt(0)" ::: "memory");
    __syncthreads();
    cur ^= 1;
  }

  const int arow0 = (b_fixed < 0) ? b * 2048 : 0;
#pragma unroll
  for (int qt = 0; qt < 2; ++qt) {
    float inv[4];
#pragma unroll
    for (int r = 0; r < 4; ++r) inv[r] = 1.0f / lacc[qt][r];
#pragma unroll
    for (int n = 0; n < 4; ++n)
#pragma unroll
      for (int r = 0; r < 4; ++r) {
        const int srow = qblk * 128 + wave * 32 + qt * 16 + quad * 4 + r;
        const size_t idx = ((size_t)(arow0 + srow)) * 1024 + h * 64 + n * 16 + col;
        attn[idx] = f2b(o[qt][n][r] * inv[r]);
      }
  }
}

// ---------------- K3a: output projection, all-bf16 staging ----------------
__global__ __launch_bounds__(256, 2) void k_proj_a(
    const u16* __restrict__ attn, const u16* __restrict__ wb,
    const float* __restrict__ bproj, float* __restrict__ out) {
  __shared__ __align__(16) u16 Asm[128 * 32];
  __shared__ __align__(16) u16 Bsm[128 * 32];
  const int bn = blockIdx.x;  // 0..7
  const int bm = blockIdx.y;  // 0..63
  const int tid = threadIdx.x;
  const int wave = tid >> 6, lane = tid & 63;
  const int col = lane & 15, quad = lane >> 4;
  const int b = bm >> 4;
  const int s0 = (bm & 15) * 128;
  const int c0 = wave * 2;
  const int srow0 = c0 * 16 + (lane >> 2);
  const int kc = (lane & 3) * 8;
  const u16* gA0 = attn + (size_t)(bm * 128 + srow0) * 1024 + kc;
  const u16* gA1 = attn + (size_t)(bm * 128 + srow0 + 16) * 1024 + kc;
  const u16* gB0 = wb + (size_t)(bn * 128 + srow0) * 1024 + kc;
  const u16* gB1 = wb + (size_t)(bn * 128 + srow0 + 16) * 1024 + kc;
  u16* lA0 = Asm + c0 * 512;
  u16* lA1 = Asm + c0 * 512 + 512;
  u16* lB0 = Bsm + c0 * 512;
  u16* lB1 = Bsm + c0 * 512 + 512;
  const int wm = (wave >> 1) * 64, wn = (wave & 1) * 64;

  f32x4 acc[4][4];
#pragma unroll
  for (int i = 0; i < 4; ++i)
#pragma unroll
    for (int j = 0; j < 4; ++j) acc[i][j] = f32x4{0.f, 0.f, 0.f, 0.f};

  for (int k0 = 0; k0 < 1024; k0 += 32) {
    __syncthreads();
    gld16(gA0 + k0, lA0);
    gld16(gA1 + k0, lA1);
    gld16(gB0 + k0, lB0);
    gld16(gB1 + k0, lB1);
    __builtin_amdgcn_s_waitcnt(0);
    __syncthreads();
    bf16x8 af[4], bfr[4];
#pragma unroll
    for (int i = 0; i < 4; ++i)
      af[i] = *(const bf16x8*)(Asm + (wm + i * 16 + col) * 32 + quad * 8);
#pragma unroll
    for (int j = 0; j < 4; ++j)
      bfr[j] = *(const bf16x8*)(Bsm + (wn + j * 16 + col) * 32 + quad * 8);
#pragma unroll
    for (int i = 0; i < 4; ++i)
#pragma unroll
      for (int j = 0; j < 4; ++j)
        acc[i][j] = __builtin_amdgcn_mfma_f32_16x16x32_bf16(af[i], bfr[j], acc[i][j], 0, 0, 0);
  }

#pragma unroll
  for (int j = 0; j < 4; ++j) {
    const int n = bn * 128 + wn + j * 16 + col;
    const float bias = bproj[n];
#pragma unroll
    for (int i = 0; i < 4; ++i) {
      const int srow = s0 + wm + i * 16 + quad * 4;
#pragma unroll
      for (int r = 0; r < 4; ++r)
        out[(size_t)((srow + r) * 4 + b) * 1024 + n] = acc[i][j][r] + bias;
    }
  }
}

// ---------------- K3b: output projection, inline-convert B (fallback) ----------------
__global__ __launch_bounds__(256, 2) void k_proj_f32(
    const u16* __restrict__ attn, const float* __restrict__ Wproj,
    const float* __restrict__ bproj, float* __restrict__ out, int b_fixed) {
  __shared__ __align__(16) u16 Asm[128 * 32];
  __shared__ __align__(16) u16 Bsm[128 * 32];
  const int bn = blockIdx.x;
  const int bm = blockIdx.y;
  const int tid = threadIdx.x;
  const int wave = tid >> 6, lane = tid & 63;
  const int col = lane & 15, quad = lane >> 4;
  int b, s0;
  if (b_fixed < 0) { b = bm >> 4; s0 = (bm & 15) * 128; }
  else             { b = b_fixed; s0 = bm * 128; }

  const int c0 = wave * 2;
  const int srow0 = c0 * 16 + (lane >> 2);
  const int kc = (lane & 3) * 8;
  const u16* gA0 = attn + (size_t)(bm * 128 + srow0) * 1024 + kc;
  const u16* gA1 = attn + (size_t)(bm * 128 + srow0 + 16) * 1024 + kc;
  u16* lA0 = Asm + c0 * 512;
  u16* lA1 = Asm + c0 * 512 + 512;
  const int brow = tid >> 1;
  const int kseg = (tid & 1) * 16;
  const float* gB = Wproj + (size_t)(bn * 128 + brow) * 1024 + kseg;
  u16* lB = Bsm + brow * 32 + kseg;
  const int wm = (wave >> 1) * 64, wn = (wave & 1) * 64;

  f32x4 acc[4][4];
#pragma unroll
  for (int i = 0; i < 4; ++i)
#pragma unroll
    for (int j = 0; j < 4; ++j) acc[i][j] = f32x4{0.f, 0.f, 0.f, 0.f};

  for (int k0 = 0; k0 < 1024; k0 += 32) {
    float4 bv[4];
#pragma unroll
    for (int u = 0; u < 4; ++u) bv[u] = *(const float4*)(gB + k0 + u * 4);
    __syncthreads();
    gld16(gA0 + k0, lA0);
    gld16(gA1 + k0, lA1);
    cvt16_store(bv, lB);
    __builtin_amdgcn_s_waitcnt(0);
    __syncthreads();
    bf16x8 af[4], bfr[4];
#pragma unroll
    for (int i = 0; i < 4; ++i)
      af[i] = *(const bf16x8*)(Asm + (wm + i * 16 + col) * 32 + quad * 8);
#pragma unroll
    for (int j = 0; j < 4; ++j)
      bfr[j] = *(const bf16x8*)(Bsm + (wn + j * 16 + col) * 32 + quad * 8);
#pragma unroll
    for (int i = 0; i < 4; ++i)
#pragma unroll
      for (int j = 0; j < 4; ++j)
        acc[i][j] = __builtin_amdgcn_mfma_f32_16x16x32_bf16(af[i], bfr[j], acc[i][j], 0, 0, 0);
  }

#pragma unroll
  for (int j = 0; j < 4; ++j) {
    const int n = bn * 128 + wn + j * 16 + col;
    const float bias = bproj[n];
#pragma unroll
    for (int i = 0; i < 4; ++i) {
      const int srow = s0 + wm + i * 16 + quad * 4;
#pragma unroll
      for (int r = 0; r < 4; ++r)
        out[(size_t)((srow + r) * 4 + b) * 1024 + n] = acc[i][j][r] + bias;
    }
  }
}

extern "C" void kernel_launch(void* const* d_in, const int* in_sizes, int n_in,
                              void* d_out, int out_size, void* d_ws, size_t ws_size,
                              hipStream_t stream) {
  const float* inp = (const float*)d_in[0];
  const int* mask = (const int*)d_in[1];
  const float* Wqkv = (const float*)d_in[2];
  const float* bqkv = (const float*)d_in[3];
  const float* Wproj = (const float*)d_in[4];
  const float* bproj = (const float*)d_in[5];
  float* out = (float*)d_out;

  const size_t FULLSZ = (size_t)BATCH * NHEAD * SEQ * DHEAD;  // 8388608 elems
  const size_t WQKV_E = (size_t)3 * DIM * DIM;                // 3145728
  const size_t WPROJ_E = (size_t)DIM * DIM;                   // 1048576
  const size_t pathA_bytes = (4 * FULLSZ + WQKV_E + WPROJ_E) * sizeof(u16);  // 75.5 MB

  if (ws_size >= pathA_bytes) {
    // Path A: convert-once + all-async-bf16 GEMMs.
    u16* q = (u16*)d_ws;
    u16* kk = q + FULLSZ;
    u16* v = kk + FULLSZ;
    u16* xb = v + FULLSZ;      // converted inp; later overwritten as attn buffer
    u16* attn = xb;            // alias — k_attn writes after k_qkv_a finished reading
    u16* wqkvb = xb + FULLSZ;
    u16* wprojb = wqkvb + WQKV_E;
    k_cvt<<<dim3(12288), 256, 0, stream>>>(inp, Wqkv, Wproj, xb, wqkvb, wprojb);
    k_qkv_a<<<dim3(24, 64), 256, 0, stream>>>(xb, wqkvb, bqkv, q, kk, v);
    k_attn<<<dim3(1024), 256, 0, stream>>>(q, kk, v, mask, attn, -1);
    k_proj_a<<<dim3(8, 64), 256, 0, stream>>>(attn, wprojb, bproj, out);
  } else if (ws_size >= 4 * FULLSZ * sizeof(u16)) {
    // Path B: proven R5 pipeline (inline f32 convert).
    u16* q = (u16*)d_ws;
    u16* kk = q + FULLSZ;
    u16* v = kk + FULLSZ;
    u16* attn = v + FULLSZ;
    k_qkv_f32<<<dim3(24, 64), 256, 0, stream>>>(inp, Wqkv, bqkv, q, kk, v, -1);
    k_attn<<<dim3(1024), 256, 0, stream>>>(q, kk, v, mask, attn, -1);
    k_proj_f32<<<dim3(8, 64), 256, 0, stream>>>(attn, Wproj, bproj, out, -1);
  } else {
    // Path C: per-batch pipeline, 16 MiB workspace.
    const size_t BSZ = (size_t)NHEAD * SEQ * DHEAD;
    u16* q = (u16*)d_ws;
    u16* kk = q + BSZ;
    u16* v = kk + BSZ;
    u16* attn = v + BSZ;
    for (int b = 0; b < BATCH; ++b) {
      k_qkv_f32<<<dim3(24, 16), 256, 0, stream>>>(inp, Wqkv, bqkv, q, kk, v, b);
      k_attn<<<dim3(256), 256, 0, stream>>>(q, kk, v, mask, attn, b);
      k_proj_f32<<<dim3(8, 16), 256, 0, stream>>>(attn, Wproj, bproj, out, b);
    }
  }
}